// Round 9
// baseline (158.568 us; speedup 1.0000x reference)
//
#include <hip/hip_runtime.h>
#include <math.h>

#define NN   4096            // N = V*B
#define BD   2048            // B
#define DF   128             // D
#define INV_T (1.0f/0.07f)
#define CAND_CAP 128         // candidates z > max-1 (superset of support, actual ~1-3)
#define GRAM_BLOCKS 528      // 32*33/2 upper-triangle 128x128 tiles

typedef __attribute__((ext_vector_type(8))) short short8v;   // 8 x bf16
typedef __attribute__((ext_vector_type(4))) float float4v;
typedef float f4a __attribute__((ext_vector_type(4), aligned(4)));   // 4B-aligned
typedef float f4n __attribute__((ext_vector_type(4)));               // 16B-aligned native

__device__ inline unsigned short f2bf_rne(float x) {
  unsigned int u = __float_as_uint(x);
  u = (u + 0x7FFFu + ((u >> 16) & 1u)) >> 16;
  return (unsigned short)u;
}

// ---------------- Kernel 1: sparsemax + fused prep + sparse Z-correction -----
// One block per row.
//  * wave 0 normalizes feat[row]: bf16 -> fbf (for k_gram), fp32 -> LDS (corr)
//  * tau via exact monotone Newton on the candidate set {z > max-1} (support
//    superset, ~1-3 elems); finitely convergent (== support-set refinement)
//  * nt loads on attn (read-once) and nt stores on ms (write-once)
//  * Zv[row] = -sum_supp exp(sim-1/T)*ms  (plain store; k_gram atomicAdds Z0)
//  * block 0 zeroes k_gram's completion counter (ws is re-poisoned each call)
__global__ __launch_bounds__(256) void k_sparsemax(
    const float* __restrict__ attn,
    const float* __restrict__ feat,
    unsigned short* __restrict__ fbf,
    float* __restrict__ msOut,   // d_out + 1
    float* __restrict__ Zv,
    unsigned int* __restrict__ doneCnt) {
  __shared__ float redM[4];
  __shared__ float cand[CAND_CAP];
  __shared__ int   cidx[CAND_CAP];
  __shared__ int ccnt;
  __shared__ float tauS;
  __shared__ float corrS[4];
  __shared__ float2 fN[64];          // normalized fp32 feature row (128 floats)
  int row  = blockIdx.x;
  int tid  = threadIdx.x;
  int lane = tid & 63, wv = tid >> 6;

  if (row == 0 && tid == 0) *doneCnt = 0u;   // init for k_gram last-block logic

  // ---- fused prep (wave 0 only) ----
  if (wv == 0) {
    float2 v = ((const float2*)(feat + (size_t)row * DF))[lane];
    float ss = v.x * v.x + v.y * v.y;
    #pragma unroll
    for (int off = 1; off < 64; off <<= 1) ss += __shfl_xor(ss, off, 64);
    float inv = rsqrtf(ss);
    float2 nv; nv.x = v.x * inv; nv.y = v.y * inv;
    ushort2 o; o.x = f2bf_rne(nv.x); o.y = f2bf_rne(nv.y);
    ((ushort2*)(fbf + (size_t)row * DF))[lane] = o;
    fN[lane] = nv;
  }

  const f4n* arow = (const f4n*)(attn + (size_t)row * NN);
  int rb = row & (BD - 1);
  float z[16];
  #pragma unroll
  for (int u = 0; u < 4; ++u) {
    int q = u * 256 + tid;            // float4 index: perfectly coalesced
    f4n a = __builtin_nontemporal_load(arow + q);
    int j = q * 4;
    z[4*u+0] = (((j+0) & (BD-1)) == rb) ? 0.f : a.x * INV_T;
    z[4*u+1] = (((j+1) & (BD-1)) == rb) ? 0.f : a.y * INV_T;
    z[4*u+2] = (((j+2) & (BD-1)) == rb) ? 0.f : a.z * INV_T;
    z[4*u+3] = (((j+3) & (BD-1)) == rb) ? 0.f : a.w * INV_T;
  }
  // row max
  float m = z[0];
  #pragma unroll
  for (int u = 1; u < 16; ++u) m = fmaxf(m, z[u]);
  #pragma unroll
  for (int off = 1; off < 64; off <<= 1) m = fmaxf(m, __shfl_xor(m, off, 64));
  if (lane == 0) redM[wv] = m;
  if (tid == 0) ccnt = 0;
  __syncthreads();                                      // barrier 1
  m = fmaxf(fmaxf(redM[0], redM[1]), fmaxf(redM[2], redM[3]));

  // collect candidates z > m-1 (rare; divergence negligible)
  float thresh = m - 1.0f;
  #pragma unroll
  for (int u = 0; u < 4; ++u) {
    #pragma unroll
    for (int t = 0; t < 4; ++t) {
      if (z[4*u+t] > thresh) {
        int slot = atomicAdd(&ccnt, 1);
        if (slot < CAND_CAP) {
          cand[slot] = z[4*u+t];
          cidx[slot] = (u * 256 + tid) * 4 + t;
        }
      }
    }
  }
  __syncthreads();                                      // barrier 2

  if (tid == 0) {
    int nc = min(ccnt, CAND_CAP);
    float tau = thresh;
    #pragma unroll 1
    for (int it = 0; it < 32; ++it) {
      float S = 0.f; float C = 0.f;
      for (int e = 0; e < nc; ++e) {
        float v = cand[e];
        if (v > tau) { S += v; C += 1.f; }
      }
      float nt = (C > 0.f) ? (S - 1.0f) / C : tau;
      if (nt == tau) break;
      tau = nt;
    }
    tauS = tau;
  }
  __syncthreads();                                      // barrier 3
  float tau = tauS;

  // branch-free vectorized nt ms store (4B-aligned dwordx4; d_out+1 base)
  float* orow = msOut + (size_t)row * NN;
  #pragma unroll
  for (int u = 0; u < 4; ++u) {
    int j = (u * 256 + tid) * 4;
    f4a v;
    v.x = fmaxf(z[4*u+0] - tau, 0.f);
    v.y = fmaxf(z[4*u+1] - tau, 0.f);
    v.z = fmaxf(z[4*u+2] - tau, 0.f);
    v.w = fmaxf(z[4*u+3] - tau, 0.f);
    __builtin_nontemporal_store(v, (f4a*)(orow + j));
  }

  // fused correction: waves split support entries; fp32 dot over 128 dims
  int nc = min(ccnt, CAND_CAP);
  float2 fi = fN[lane];
  float corr = 0.f;
  for (int e = wv; e < nc; e += 4) {
    float msv = cand[e] - tau;
    if (msv <= 0.f) continue;
    int j = cidx[e];
    float2 g = ((const float2*)(feat + (size_t)j * DF))[lane];
    float dt = fi.x * g.x + fi.y * g.y;
    float sj = g.x * g.x + g.y * g.y;
    #pragma unroll
    for (int off = 1; off < 64; off <<= 1) {
      dt += __shfl_xor(dt, off, 64);
      sj += __shfl_xor(sj, off, 64);
    }
    float s = dt * rsqrtf(sj);
    corr += __expf(s * INV_T - INV_T) * msv;
  }
  if (lane == 0) corrS[wv] = corr;
  __syncthreads();                                      // barrier 4
  if (tid == 0) {
    float tot = (corrS[0] + corrS[1]) + (corrS[2] + corrS[3]);
    Zv[row] = -tot;                  // plain store: initializes Z for k_gram
  }
}

// ---------------- Kernel 2: symmetric MFMA Gram + Z0 + numer + loss ----------
// Upper-triangle 128x128 tiles only (528 blocks). Each element (i<j) credits
// exp(sim-1/T) to Z_i (row-reduce over c-lanes) and Z_j (col-reduce over
// quads via shfl 16/32). numer written (AGENT-scope, cross-XCD visible) for
// both ends of the positive pair. Last block to finish computes the loss
// (device-scope counter; AGENT-scope loads bypass stale per-XCD L2).
__global__ __launch_bounds__(256) void k_gram(
    const unsigned short* __restrict__ fbf, float* __restrict__ Zv,
    float* __restrict__ numer, unsigned int* __restrict__ doneCnt,
    float* __restrict__ out) {
  // decode linear block id -> upper-tri tile (bi <= bj), 32 block-rows
  int t = blockIdx.x, bi = 0, L = 32;
  while (t >= L) { t -= L; --L; ++bi; }
  int bj = bi + t;

  int tid = threadIdx.x;
  int wave = tid >> 6, lane = tid & 63;
  int c = lane & 15, quad = lane >> 4;
  int wi = wave >> 1, wj = wave & 1;
  bool dead = (bi == bj && wi > wj);    // below-diagonal wave: no tile work
                                        // (must NOT return: syncthreads below)
  if (!dead) {
    int i0 = bi * 128 + wi * 64;
    int j0 = bj * 128 + wj * 64;

    const unsigned short* aBase = fbf + (size_t)(i0 + c) * DF + quad * 8;
    const unsigned short* bBase = fbf + (size_t)(j0 + c) * DF + quad * 8;

    float4v acc[4][4];
    #pragma unroll
    for (int m = 0; m < 4; ++m)
      #pragma unroll
      for (int n = 0; n < 4; ++n) acc[m][n] = (float4v){0.f, 0.f, 0.f, 0.f};

    #pragma unroll
    for (int k0 = 0; k0 < DF; k0 += 32) {
      short8v afr[4], bfr[4];
      #pragma unroll
      for (int m = 0; m < 4; ++m)
        afr[m] = *(const short8v*)(aBase + (size_t)(m * 16) * DF + k0);
      #pragma unroll
      for (int n = 0; n < 4; ++n)
        bfr[n] = *(const short8v*)(bBase + (size_t)(n * 16) * DF + k0);
      #pragma unroll
      for (int m = 0; m < 4; ++m)
        #pragma unroll
        for (int n = 0; n < 4; ++n)
          acc[m][n] = __builtin_amdgcn_mfma_f32_16x16x32_bf16(
              afr[m], bfr[n], acc[m][n], 0, 0, 0);
    }

    // epilogue (C/D: col=lane&15, row=quad*4+r); each unordered pair once
    float colacc[4] = {0.f, 0.f, 0.f, 0.f};
    #pragma unroll
    for (int m = 0; m < 4; ++m) {
      #pragma unroll
      for (int r = 0; r < 4; ++r) {
        int i = i0 + m * 16 + quad * 4 + r;
        float zrow = 0.f;
        #pragma unroll
        for (int n = 0; n < 4; ++n) {
          int j = j0 + n * 16 + c;
          float simv = acc[m][n][r] * INV_T - INV_T;
          float e = (j > i) ? __expf(simv) : 0.f;
          zrow += e;
          colacc[n] += e;
          if (j - i == BD) {
            __hip_atomic_store(&numer[i], simv, __ATOMIC_RELAXED,
                               __HIP_MEMORY_SCOPE_AGENT);
            __hip_atomic_store(&numer[j], simv, __ATOMIC_RELAXED,
                               __HIP_MEMORY_SCOPE_AGENT);
          }
        }
        zrow += __shfl_xor(zrow, 1, 64);
        zrow += __shfl_xor(zrow, 2, 64);
        zrow += __shfl_xor(zrow, 4, 64);
        zrow += __shfl_xor(zrow, 8, 64);
        if (c == 0) atomicAdd(&Zv[i], zrow);
      }
    }
    #pragma unroll
    for (int n = 0; n < 4; ++n) {
      float v = colacc[n];
      v += __shfl_xor(v, 16, 64);
      v += __shfl_xor(v, 32, 64);
      if (quad == 0) atomicAdd(&Zv[j0 + n * 16 + c], v);
    }
  }

  // ---- last-block loss reduction ----
  __shared__ unsigned int isLast;
  __shared__ float red[4];
  if (tid == 0) {
    __threadfence();                       // release our Zv/numer writes
    unsigned int old = atomicAdd(doneCnt, 1u);
    isLast = (old == GRAM_BLOCKS - 1) ? 1u : 0u;
  }
  __syncthreads();
  if (isLast) {
    __threadfence();                       // acquire all blocks' writes
    float acc = 0.f;
    for (int i = tid; i < NN; i += 256) {
      float nu = __hip_atomic_load(&numer[i], __ATOMIC_RELAXED,
                                   __HIP_MEMORY_SCOPE_AGENT);
      float zz = __hip_atomic_load(&Zv[i], __ATOMIC_RELAXED,
                                   __HIP_MEMORY_SCOPE_AGENT);
      acc += nu - logf(zz);
    }
    #pragma unroll
    for (int off = 1; off < 64; off <<= 1) acc += __shfl_xor(acc, off, 64);
    if (lane == 0) red[wave] = acc;
    __syncthreads();
    if (tid == 0) {
      float tt = (red[0] + red[1]) + (red[2] + red[3]);
      out[0] = -tt / (float)NN;
    }
  }
}

extern "C" void kernel_launch(void* const* d_in, const int* in_sizes, int n_in,
                              void* d_out, int out_size, void* d_ws, size_t ws_size,
                              hipStream_t stream) {
  const float* feat = (const float*)d_in[0];   // (2048, 2, 128) f32 -> (4096,128)
  const float* attn = (const float*)d_in[1];   // (4096, 4096) f32
  float* out = (float*)d_out;                  // [loss, masked_scores(16.7M)]
  float* msOut = out + 1;

  float* Zv    = (float*)d_ws;                 // NN
  float* numer = Zv + NN;                      // NN
  unsigned int* doneCnt = (unsigned int*)(numer + NN);  // 1
  unsigned short* fbf = (unsigned short*)(doneCnt + 64); // NN*DF bf16

  k_sparsemax<<<dim3(4096), dim3(256), 0, stream>>>(attn, feat, fbf, msOut, Zv,
                                                    doneCnt);
  k_gram<<<dim3(GRAM_BLOCKS), dim3(256), 0, stream>>>(fbf, Zv, numer, doneCnt,
                                                      out);
}

// Round 10
// 153.134 us; speedup vs baseline: 1.0355x; 1.0355x over previous
//
#include <hip/hip_runtime.h>
#include <math.h>

#define NN   4096            // N = V*B
#define BD   2048            // B
#define DF   128             // D
#define INV_T (1.0f/0.07f)
#define CAND_CAP 128         // candidates z > max-1 (superset of support, actual ~1-3)
#define GRAM_BLOCKS 528      // 32*33/2 upper-triangle 128x128 tiles

typedef __attribute__((ext_vector_type(8))) short short8v;   // 8 x bf16
typedef __attribute__((ext_vector_type(4))) float float4v;
typedef float f4a __attribute__((ext_vector_type(4), aligned(4)));  // 4B-aligned float4

__device__ inline unsigned short f2bf_rne(float x) {
  unsigned int u = __float_as_uint(x);
  u = (u + 0x7FFFu + ((u >> 16) & 1u)) >> 16;
  return (unsigned short)u;
}

// ---------------- Kernel 1: sparsemax + fused prep + sparse Z-correction -----
// One block per row.
//  * wave 0 normalizes feat[row]: bf16 -> fbf (for k_gram), fp32 -> LDS (corr)
//  * tau via exact monotone Newton on the candidate set {z > max-1} (support
//    superset, ~1-3 elems); finitely convergent (== support-set refinement)
//  * Zv[row] = -sum_supp exp(sim-1/T)*ms  (plain store; k_gram atomicAdds Z0)
//  * block 0 zeroes k_gram's completion counter (ws is re-poisoned each call)
// NOTE R9 lesson: non-temporal hints on the attn load / ms store REGRESSED
// (+10us): nt defeats L2 write-back overlap on the 64MB ms stream. Plain ops.
__global__ __launch_bounds__(256) void k_sparsemax(
    const float* __restrict__ attn,
    const float* __restrict__ feat,
    unsigned short* __restrict__ fbf,
    float* __restrict__ msOut,   // d_out + 1
    float* __restrict__ Zv,
    unsigned int* __restrict__ doneCnt) {
  __shared__ float redM[4];
  __shared__ float cand[CAND_CAP];
  __shared__ int   cidx[CAND_CAP];
  __shared__ int ccnt;
  __shared__ float tauS;
  __shared__ float corrS[4];
  __shared__ float2 fN[64];          // normalized fp32 feature row (128 floats)
  int row  = blockIdx.x;
  int tid  = threadIdx.x;
  int lane = tid & 63, wv = tid >> 6;

  if (row == 0 && tid == 0) *doneCnt = 0u;   // init for k_gram last-block logic

  // ---- fused prep (wave 0 only) ----
  if (wv == 0) {
    float2 v = ((const float2*)(feat + (size_t)row * DF))[lane];
    float ss = v.x * v.x + v.y * v.y;
    #pragma unroll
    for (int off = 1; off < 64; off <<= 1) ss += __shfl_xor(ss, off, 64);
    float inv = rsqrtf(ss);
    float2 nv; nv.x = v.x * inv; nv.y = v.y * inv;
    ushort2 o; o.x = f2bf_rne(nv.x); o.y = f2bf_rne(nv.y);
    ((ushort2*)(fbf + (size_t)row * DF))[lane] = o;
    fN[lane] = nv;
  }

  const float4* arow = (const float4*)(attn + (size_t)row * NN);
  int rb = row & (BD - 1);
  float z[16];
  #pragma unroll
  for (int u = 0; u < 4; ++u) {
    int q = u * 256 + tid;            // float4 index: perfectly coalesced
    float4 a = arow[q];
    int j = q * 4;
    z[4*u+0] = (((j+0) & (BD-1)) == rb) ? 0.f : a.x * INV_T;
    z[4*u+1] = (((j+1) & (BD-1)) == rb) ? 0.f : a.y * INV_T;
    z[4*u+2] = (((j+2) & (BD-1)) == rb) ? 0.f : a.z * INV_T;
    z[4*u+3] = (((j+3) & (BD-1)) == rb) ? 0.f : a.w * INV_T;
  }
  // row max
  float m = z[0];
  #pragma unroll
  for (int u = 1; u < 16; ++u) m = fmaxf(m, z[u]);
  #pragma unroll
  for (int off = 1; off < 64; off <<= 1) m = fmaxf(m, __shfl_xor(m, off, 64));
  if (lane == 0) redM[wv] = m;
  if (tid == 0) ccnt = 0;
  __syncthreads();                                      // barrier 1
  m = fmaxf(fmaxf(redM[0], redM[1]), fmaxf(redM[2], redM[3]));

  // collect candidates z > m-1 (rare; divergence negligible)
  float thresh = m - 1.0f;
  #pragma unroll
  for (int u = 0; u < 4; ++u) {
    #pragma unroll
    for (int t = 0; t < 4; ++t) {
      if (z[4*u+t] > thresh) {
        int slot = atomicAdd(&ccnt, 1);
        if (slot < CAND_CAP) {
          cand[slot] = z[4*u+t];
          cidx[slot] = (u * 256 + tid) * 4 + t;
        }
      }
    }
  }
  __syncthreads();                                      // barrier 2

  if (tid == 0) {
    int nc = min(ccnt, CAND_CAP);
    float tau = thresh;
    #pragma unroll 1
    for (int it = 0; it < 32; ++it) {
      float S = 0.f; float C = 0.f;
      for (int e = 0; e < nc; ++e) {
        float v = cand[e];
        if (v > tau) { S += v; C += 1.f; }
      }
      float nt = (C > 0.f) ? (S - 1.0f) / C : tau;
      if (nt == tau) break;
      tau = nt;
    }
    tauS = tau;
  }
  __syncthreads();                                      // barrier 3
  float tau = tauS;

  // branch-free vectorized ms store (4B-aligned dwordx4; d_out+1 base)
  float* orow = msOut + (size_t)row * NN;
  #pragma unroll
  for (int u = 0; u < 4; ++u) {
    int j = (u * 256 + tid) * 4;
    f4a v;
    v.x = fmaxf(z[4*u+0] - tau, 0.f);
    v.y = fmaxf(z[4*u+1] - tau, 0.f);
    v.z = fmaxf(z[4*u+2] - tau, 0.f);
    v.w = fmaxf(z[4*u+3] - tau, 0.f);
    *((f4a*)(orow + j)) = v;
  }

  // fused correction: waves split support entries; fp32 dot over 128 dims
  int nc = min(ccnt, CAND_CAP);
  float2 fi = fN[lane];
  float corr = 0.f;
  for (int e = wv; e < nc; e += 4) {
    float msv = cand[e] - tau;
    if (msv <= 0.f) continue;
    int j = cidx[e];
    float2 g = ((const float2*)(feat + (size_t)j * DF))[lane];
    float dt = fi.x * g.x + fi.y * g.y;
    float sj = g.x * g.x + g.y * g.y;
    #pragma unroll
    for (int off = 1; off < 64; off <<= 1) {
      dt += __shfl_xor(dt, off, 64);
      sj += __shfl_xor(sj, off, 64);
    }
    float s = dt * rsqrtf(sj);
    corr += __expf(s * INV_T - INV_T) * msv;
  }
  if (lane == 0) corrS[wv] = corr;
  __syncthreads();                                      // barrier 4
  if (tid == 0) {
    float tot = (corrS[0] + corrS[1]) + (corrS[2] + corrS[3]);
    Zv[row] = -tot;                  // plain store: initializes Z for k_gram
  }
}

// ---------------- Kernel 2: symmetric MFMA Gram + Z0 + numer + loss ----------
// Upper-triangle 128x128 tiles only (528 blocks). Each element (i<j) credits
// exp(sim-1/T) to Z_i (row-reduce over c-lanes) and Z_j (col-reduce over
// quads via shfl 16/32). numer written (AGENT-scope, cross-XCD visible) for
// both ends of the positive pair. Last block to finish computes the loss
// (device-scope counter; AGENT-scope loads bypass stale per-XCD L2).
__global__ __launch_bounds__(256) void k_gram(
    const unsigned short* __restrict__ fbf, float* __restrict__ Zv,
    float* __restrict__ numer, unsigned int* __restrict__ doneCnt,
    float* __restrict__ out) {
  // decode linear block id -> upper-tri tile (bi <= bj), 32 block-rows
  int t = blockIdx.x, bi = 0, L = 32;
  while (t >= L) { t -= L; --L; ++bi; }
  int bj = bi + t;

  int tid = threadIdx.x;
  int wave = tid >> 6, lane = tid & 63;
  int c = lane & 15, quad = lane >> 4;
  int wi = wave >> 1, wj = wave & 1;
  bool dead = (bi == bj && wi > wj);    // below-diagonal wave: no tile work
                                        // (must NOT return: syncthreads below)
  if (!dead) {
    int i0 = bi * 128 + wi * 64;
    int j0 = bj * 128 + wj * 64;

    const unsigned short* aBase = fbf + (size_t)(i0 + c) * DF + quad * 8;
    const unsigned short* bBase = fbf + (size_t)(j0 + c) * DF + quad * 8;

    float4v acc[4][4];
    #pragma unroll
    for (int m = 0; m < 4; ++m)
      #pragma unroll
      for (int n = 0; n < 4; ++n) acc[m][n] = (float4v){0.f, 0.f, 0.f, 0.f};

    #pragma unroll
    for (int k0 = 0; k0 < DF; k0 += 32) {
      short8v afr[4], bfr[4];
      #pragma unroll
      for (int m = 0; m < 4; ++m)
        afr[m] = *(const short8v*)(aBase + (size_t)(m * 16) * DF + k0);
      #pragma unroll
      for (int n = 0; n < 4; ++n)
        bfr[n] = *(const short8v*)(bBase + (size_t)(n * 16) * DF + k0);
      #pragma unroll
      for (int m = 0; m < 4; ++m)
        #pragma unroll
        for (int n = 0; n < 4; ++n)
          acc[m][n] = __builtin_amdgcn_mfma_f32_16x16x32_bf16(
              afr[m], bfr[n], acc[m][n], 0, 0, 0);
    }

    // epilogue (C/D: col=lane&15, row=quad*4+r); each unordered pair once
    float colacc[4] = {0.f, 0.f, 0.f, 0.f};
    #pragma unroll
    for (int m = 0; m < 4; ++m) {
      #pragma unroll
      for (int r = 0; r < 4; ++r) {
        int i = i0 + m * 16 + quad * 4 + r;
        float zrow = 0.f;
        #pragma unroll
        for (int n = 0; n < 4; ++n) {
          int j = j0 + n * 16 + c;
          float simv = acc[m][n][r] * INV_T - INV_T;
          float e = (j > i) ? __expf(simv) : 0.f;
          zrow += e;
          colacc[n] += e;
          if (j - i == BD) {
            __hip_atomic_store(&numer[i], simv, __ATOMIC_RELAXED,
                               __HIP_MEMORY_SCOPE_AGENT);
            __hip_atomic_store(&numer[j], simv, __ATOMIC_RELAXED,
                               __HIP_MEMORY_SCOPE_AGENT);
          }
        }
        zrow += __shfl_xor(zrow, 1, 64);
        zrow += __shfl_xor(zrow, 2, 64);
        zrow += __shfl_xor(zrow, 4, 64);
        zrow += __shfl_xor(zrow, 8, 64);
        if (c == 0) atomicAdd(&Zv[i], zrow);
      }
    }
    #pragma unroll
    for (int n = 0; n < 4; ++n) {
      float v = colacc[n];
      v += __shfl_xor(v, 16, 64);
      v += __shfl_xor(v, 32, 64);
      if (quad == 0) atomicAdd(&Zv[j0 + n * 16 + c], v);
    }
  }

  // ---- last-block loss reduction ----
  __shared__ unsigned int isLast;
  __shared__ float red[4];
  if (tid == 0) {
    __threadfence();                       // release our Zv/numer writes
    unsigned int old = atomicAdd(doneCnt, 1u);
    isLast = (old == GRAM_BLOCKS - 1) ? 1u : 0u;
  }
  __syncthreads();
  if (isLast) {
    __threadfence();                       // acquire all blocks' writes
    float acc = 0.f;
    for (int i = tid; i < NN; i += 256) {
      float nu = __hip_atomic_load(&numer[i], __ATOMIC_RELAXED,
                                   __HIP_MEMORY_SCOPE_AGENT);
      float zz = __hip_atomic_load(&Zv[i], __ATOMIC_RELAXED,
                                   __HIP_MEMORY_SCOPE_AGENT);
      acc += nu - logf(zz);
    }
    #pragma unroll
    for (int off = 1; off < 64; off <<= 1) acc += __shfl_xor(acc, off, 64);
    if (lane == 0) red[wave] = acc;
    __syncthreads();
    if (tid == 0) {
      float tt = (red[0] + red[1]) + (red[2] + red[3]);
      out[0] = -tt / (float)NN;
    }
  }
}

extern "C" void kernel_launch(void* const* d_in, const int* in_sizes, int n_in,
                              void* d_out, int out_size, void* d_ws, size_t ws_size,
                              hipStream_t stream) {
  const float* feat = (const float*)d_in[0];   // (2048, 2, 128) f32 -> (4096,128)
  const float* attn = (const float*)d_in[1];   // (4096, 4096) f32
  float* out = (float*)d_out;                  // [loss, masked_scores(16.7M)]
  float* msOut = out + 1;

  float* Zv    = (float*)d_ws;                 // NN
  float* numer = Zv + NN;                      // NN
  unsigned int* doneCnt = (unsigned int*)(numer + NN);  // 1
  unsigned short* fbf = (unsigned short*)(doneCnt + 64); // NN*DF bf16

  k_sparsemax<<<dim3(4096), dim3(256), 0, stream>>>(attn, feat, fbf, msOut, Zv,
                                                    doneCnt);
  k_gram<<<dim3(GRAM_BLOCKS), dim3(256), 0, stream>>>(fbf, Zv, numer, doneCnt,
                                                      out);
}

// Round 11
// 147.264 us; speedup vs baseline: 1.0768x; 1.0399x over previous
//
#include <hip/hip_runtime.h>
#include <math.h>

#define NN   4096            // N = V*B
#define BD   2048            // B
#define DF   128             // D
#define INV_T (1.0f/0.07f)
#define CAND_CAP 128         // candidates z > max-1 (superset of support, actual ~1-3)

typedef __attribute__((ext_vector_type(8))) short short8v;   // 8 x bf16
typedef __attribute__((ext_vector_type(4))) float float4v;
typedef float f4a __attribute__((ext_vector_type(4), aligned(4)));  // 4B-aligned float4

__device__ inline unsigned short f2bf_rne(float x) {
  unsigned int u = __float_as_uint(x);
  u = (u + 0x7FFFu + ((u >> 16) & 1u)) >> 16;
  return (unsigned short)u;
}

// ---------------- Kernel 1: sparsemax + fused prep + sparse Z-correction -----
// One block per row.
//  * wave 0 normalizes feat[row]: bf16 -> fbf (for k_gram), fp32 -> LDS (corr)
//  * tau via exact monotone Newton on the candidate set {z > max-1} (support
//    superset, ~1-3 elems); finitely convergent (== support-set refinement)
//  * Zv[row] = -sum_supp exp(sim-1/T)*ms  (plain store; k_gram atomicAdds Z0)
// NOTE R9 lesson: non-temporal hints on the attn load / ms store REGRESSED
// (+10us total): nt defeats L2 write-back overlap on the 64MB ms stream and
// L3 absorption of the attn stream. Plain vector ops.
// NOTE R10 lesson: fusing the loss reduction into k_gram via completion
// counter + fences was neutral-to-negative; separate 1.5us k_loss is best.
__global__ __launch_bounds__(256) void k_sparsemax(
    const float* __restrict__ attn,
    const float* __restrict__ feat,
    unsigned short* __restrict__ fbf,
    float* __restrict__ msOut,   // d_out + 1
    float* __restrict__ Zv) {
  __shared__ float redM[4];
  __shared__ float cand[CAND_CAP];
  __shared__ int   cidx[CAND_CAP];
  __shared__ int ccnt;
  __shared__ float tauS;
  __shared__ float corrS[4];
  __shared__ float2 fN[64];          // normalized fp32 feature row (128 floats)
  int row  = blockIdx.x;
  int tid  = threadIdx.x;
  int lane = tid & 63, wv = tid >> 6;

  // ---- fused prep (wave 0 only) ----
  if (wv == 0) {
    float2 v = ((const float2*)(feat + (size_t)row * DF))[lane];
    float ss = v.x * v.x + v.y * v.y;
    #pragma unroll
    for (int off = 1; off < 64; off <<= 1) ss += __shfl_xor(ss, off, 64);
    float inv = rsqrtf(ss);
    float2 nv; nv.x = v.x * inv; nv.y = v.y * inv;
    ushort2 o; o.x = f2bf_rne(nv.x); o.y = f2bf_rne(nv.y);
    ((ushort2*)(fbf + (size_t)row * DF))[lane] = o;
    fN[lane] = nv;
  }

  const float4* arow = (const float4*)(attn + (size_t)row * NN);
  int rb = row & (BD - 1);
  float z[16];
  #pragma unroll
  for (int u = 0; u < 4; ++u) {
    int q = u * 256 + tid;            // float4 index: perfectly coalesced
    float4 a = arow[q];
    int j = q * 4;
    z[4*u+0] = (((j+0) & (BD-1)) == rb) ? 0.f : a.x * INV_T;
    z[4*u+1] = (((j+1) & (BD-1)) == rb) ? 0.f : a.y * INV_T;
    z[4*u+2] = (((j+2) & (BD-1)) == rb) ? 0.f : a.z * INV_T;
    z[4*u+3] = (((j+3) & (BD-1)) == rb) ? 0.f : a.w * INV_T;
  }
  // row max
  float m = z[0];
  #pragma unroll
  for (int u = 1; u < 16; ++u) m = fmaxf(m, z[u]);
  #pragma unroll
  for (int off = 1; off < 64; off <<= 1) m = fmaxf(m, __shfl_xor(m, off, 64));
  if (lane == 0) redM[wv] = m;
  if (tid == 0) ccnt = 0;
  __syncthreads();                                      // barrier 1
  m = fmaxf(fmaxf(redM[0], redM[1]), fmaxf(redM[2], redM[3]));

  // collect candidates z > m-1 (rare; divergence negligible)
  float thresh = m - 1.0f;
  #pragma unroll
  for (int u = 0; u < 4; ++u) {
    #pragma unroll
    for (int t = 0; t < 4; ++t) {
      if (z[4*u+t] > thresh) {
        int slot = atomicAdd(&ccnt, 1);
        if (slot < CAND_CAP) {
          cand[slot] = z[4*u+t];
          cidx[slot] = (u * 256 + tid) * 4 + t;
        }
      }
    }
  }
  __syncthreads();                                      // barrier 2

  if (tid == 0) {
    int nc = min(ccnt, CAND_CAP);
    float tau = thresh;
    #pragma unroll 1
    for (int it = 0; it < 32; ++it) {
      float S = 0.f; float C = 0.f;
      for (int e = 0; e < nc; ++e) {
        float v = cand[e];
        if (v > tau) { S += v; C += 1.f; }
      }
      float nt = (C > 0.f) ? (S - 1.0f) / C : tau;
      if (nt == tau) break;
      tau = nt;
    }
    tauS = tau;
  }
  __syncthreads();                                      // barrier 3
  float tau = tauS;

  // branch-free vectorized ms store (4B-aligned dwordx4; d_out+1 base)
  float* orow = msOut + (size_t)row * NN;
  #pragma unroll
  for (int u = 0; u < 4; ++u) {
    int j = (u * 256 + tid) * 4;
    f4a v;
    v.x = fmaxf(z[4*u+0] - tau, 0.f);
    v.y = fmaxf(z[4*u+1] - tau, 0.f);
    v.z = fmaxf(z[4*u+2] - tau, 0.f);
    v.w = fmaxf(z[4*u+3] - tau, 0.f);
    *((f4a*)(orow + j)) = v;
  }

  // fused correction: waves split support entries; fp32 dot over 128 dims
  int nc = min(ccnt, CAND_CAP);
  float2 fi = fN[lane];
  float corr = 0.f;
  for (int e = wv; e < nc; e += 4) {
    float msv = cand[e] - tau;
    if (msv <= 0.f) continue;
    int j = cidx[e];
    float2 g = ((const float2*)(feat + (size_t)j * DF))[lane];
    float dt = fi.x * g.x + fi.y * g.y;
    float sj = g.x * g.x + g.y * g.y;
    #pragma unroll
    for (int off = 1; off < 64; off <<= 1) {
      dt += __shfl_xor(dt, off, 64);
      sj += __shfl_xor(sj, off, 64);
    }
    float s = dt * rsqrtf(sj);
    corr += __expf(s * INV_T - INV_T) * msv;
  }
  if (lane == 0) corrS[wv] = corr;
  __syncthreads();                                      // barrier 4
  if (tid == 0) {
    float tot = (corrS[0] + corrS[1]) + (corrS[2] + corrS[3]);
    Zv[row] = -tot;                  // plain store: initializes Z for k_gram
  }
}

// ---------------- Kernel 2: symmetric MFMA Gram + Z0 + numer ----------------
// Upper-triangle 128x128 tiles only (528 blocks). Each element (i<j) credits
// exp(sim-1/T) to Z_i (row-reduce over c-lanes) and Z_j (col-reduce over
// quads via shfl 16/32). numer written for both ends of the positive pair.
__global__ __launch_bounds__(256) void k_gram(
    const unsigned short* __restrict__ fbf, float* __restrict__ Zv,
    float* __restrict__ numer) {
  // decode linear block id -> upper-tri tile (bi <= bj), 32 block-rows
  int t = blockIdx.x, bi = 0, L = 32;
  while (t >= L) { t -= L; --L; ++bi; }
  int bj = bi + t;

  int tid = threadIdx.x;
  int wave = tid >> 6, lane = tid & 63;
  int c = lane & 15, quad = lane >> 4;
  int wi = wave >> 1, wj = wave & 1;
  if (bi == bj && wi > wj) return;      // fully-below-diagonal wave: no work
  int i0 = bi * 128 + wi * 64;
  int j0 = bj * 128 + wj * 64;

  const unsigned short* aBase = fbf + (size_t)(i0 + c) * DF + quad * 8;
  const unsigned short* bBase = fbf + (size_t)(j0 + c) * DF + quad * 8;

  float4v acc[4][4];
  #pragma unroll
  for (int m = 0; m < 4; ++m)
    #pragma unroll
    for (int n = 0; n < 4; ++n) acc[m][n] = (float4v){0.f, 0.f, 0.f, 0.f};

  #pragma unroll
  for (int k0 = 0; k0 < DF; k0 += 32) {
    short8v afr[4], bfr[4];
    #pragma unroll
    for (int m = 0; m < 4; ++m)
      afr[m] = *(const short8v*)(aBase + (size_t)(m * 16) * DF + k0);
    #pragma unroll
    for (int n = 0; n < 4; ++n)
      bfr[n] = *(const short8v*)(bBase + (size_t)(n * 16) * DF + k0);
    #pragma unroll
    for (int m = 0; m < 4; ++m)
      #pragma unroll
      for (int n = 0; n < 4; ++n)
        acc[m][n] = __builtin_amdgcn_mfma_f32_16x16x32_bf16(
            afr[m], bfr[n], acc[m][n], 0, 0, 0);
  }

  // epilogue (C/D: col=lane&15, row=quad*4+r); count each unordered pair once
  float colacc[4] = {0.f, 0.f, 0.f, 0.f};
  #pragma unroll
  for (int m = 0; m < 4; ++m) {
    #pragma unroll
    for (int r = 0; r < 4; ++r) {
      int i = i0 + m * 16 + quad * 4 + r;
      float zrow = 0.f;
      #pragma unroll
      for (int n = 0; n < 4; ++n) {
        int j = j0 + n * 16 + c;
        float simv = acc[m][n][r] * INV_T - INV_T;
        float e = (j > i) ? __expf(simv) : 0.f;
        zrow += e;
        colacc[n] += e;
        if (j - i == BD) { numer[i] = simv; numer[j] = simv; }
      }
      zrow += __shfl_xor(zrow, 1, 64);
      zrow += __shfl_xor(zrow, 2, 64);
      zrow += __shfl_xor(zrow, 4, 64);
      zrow += __shfl_xor(zrow, 8, 64);
      if (c == 0) atomicAdd(&Zv[i], zrow);
    }
  }
  #pragma unroll
  for (int n = 0; n < 4; ++n) {
    float v = colacc[n];
    v += __shfl_xor(v, 16, 64);
    v += __shfl_xor(v, 32, 64);
    if (quad == 0) atomicAdd(&Zv[j0 + n * 16 + c], v);
  }
}

// ---------------- Kernel 3: finalize loss (single block) ----------------
__global__ void k_loss(const float* __restrict__ Zv,
                       const float* __restrict__ numer,
                       float* __restrict__ out) {
  float acc = 0.f;
  for (int i = threadIdx.x; i < NN; i += 256)
    acc += numer[i] - logf(Zv[i]);
  #pragma unroll
  for (int off = 1; off < 64; off <<= 1) acc += __shfl_xor(acc, off, 64);
  __shared__ float red[4];
  int wv = threadIdx.x >> 6, lane = threadIdx.x & 63;
  if (lane == 0) red[wv] = acc;
  __syncthreads();
  if (threadIdx.x == 0) {
    float t = (red[0] + red[1]) + (red[2] + red[3]);
    out[0] = -t / (float)NN;
  }
}

extern "C" void kernel_launch(void* const* d_in, const int* in_sizes, int n_in,
                              void* d_out, int out_size, void* d_ws, size_t ws_size,
                              hipStream_t stream) {
  const float* feat = (const float*)d_in[0];   // (2048, 2, 128) f32 -> (4096,128)
  const float* attn = (const float*)d_in[1];   // (4096, 4096) f32
  float* out = (float*)d_out;                  // [loss, masked_scores(16.7M)]
  float* msOut = out + 1;

  float* Zv    = (float*)d_ws;                 // NN
  float* numer = Zv + NN;                      // NN
  unsigned short* fbf = (unsigned short*)(numer + NN);  // NN*DF bf16

  k_sparsemax<<<dim3(4096), dim3(256), 0, stream>>>(attn, feat, fbf, msOut, Zv);
  k_gram<<<dim3(528), dim3(256), 0, stream>>>(fbf, Zv, numer);
  k_loss<<<dim3(1), dim3(256), 0, stream>>>(Zv, numer, out);
}